// Round 20
// baseline (606.381 us; speedup 1.0000x reference)
//
#include <hip/hip_runtime.h>
#include <math.h>

// ---------------------------------------------------------------------------
// ViT encoder block. All-single-fp16 MFMA GEMMs + attention.
// B=32, N=577, D=768, H=12, Dh=64, hid=3072, M=18464, Mq=20480 (32x640).
// R20: 256^2 BK=32 ring-2 with LDS squeezed to EXACTLY 65536B for
//      OMODE 0/1 (fc1/fc2/proj) -> 2 blocks/CU co-residency (the R19
//      69.6KB variant failed to co-schedule). Epilogues run in smaller
//      per-wave passes (fp16: 4x[32][68], fp32: 8x[16][68]); QKV-scatter
//      instantiation keeps [64][68] (69.6KB, 1 blk/CU). K-loop = R19.
// ---------------------------------------------------------------------------

typedef unsigned short u16;
typedef _Float16 f16;
typedef __attribute__((ext_vector_type(8))) _Float16 f16x8;
typedef __attribute__((ext_vector_type(4))) float f32x4;

__device__ __forceinline__ u16 f2h(float x) {            // RNE f32 -> fp16 bits
    union { f16 h; u16 u; } cv;
    cv.h = (f16)x;
    return cv.u;
}
__device__ __forceinline__ float h2f(u16 b) {
    union { u16 u; f16 h; } cv;
    cv.u = b;
    return (float)cv.h;
}
__device__ __forceinline__ void load_lds16(const u16* g, void* l) {
    __builtin_amdgcn_global_load_lds(
        (const __attribute__((address_space(1))) void*)g,
        (__attribute__((address_space(3))) void*)l, 16, 0, 0);
}
// bijective XCD-chunk swizzle (m204)
__device__ __forceinline__ int xcd_swz(int lid, int nwg) {
    const int x = lid & 7, pos = lid >> 3;
    const int q = nwg >> 3, r = nwg & 7;
    return (x < r ? x * (q + 1) : r * (q + 1) + (x - r) * q) + pos;
}

// --------------------- weight transpose + fp16 (once) ----------------------
__global__ __launch_bounds__(256)
void wprep_kernel(const float* __restrict__ W, u16* __restrict__ Th,
                  int K, int N)
{
    __shared__ float t[32][33];
    const int n0 = blockIdx.x * 32, k0 = blockIdx.y * 32;
    const int tr = threadIdx.x >> 3, tc4 = (threadIdx.x & 7) * 4;
    const float4 v = *(const float4*)&W[(size_t)(k0 + tr) * N + n0 + tc4];
    t[tr][tc4 + 0] = v.x; t[tr][tc4 + 1] = v.y;
    t[tr][tc4 + 2] = v.z; t[tr][tc4 + 3] = v.w;
    __syncthreads();
    ushort4 h;
    h.x = f2h(t[tc4 + 0][tr]);
    h.y = f2h(t[tc4 + 1][tr]);
    h.z = f2h(t[tc4 + 2][tr]);
    h.w = f2h(t[tc4 + 3][tr]);
    *(ushort4*)&Th[(size_t)(n0 + tr) * K + k0 + tc4] = h;
}

// ------------------------- LayerNorm -> single fp16 -------------------------
// pad=1: write to batch-padded row (row/577)*640 + row%577; pad=0: direct.
__global__ __launch_bounds__(256)
void ln_kernel(const float* __restrict__ x, const float* __restrict__ g,
               const float* __restrict__ beta, u16* __restrict__ oh, int pad)
{
    const int row = blockIdx.x;
    const int tid = threadIdx.x;
    const float* xr = x + (size_t)row * 768;
    const float v0 = xr[tid], v1 = xr[tid + 256], v2 = xr[tid + 512];
    float s  = v0 + v1 + v2;
    float ss = v0 * v0 + v1 * v1 + v2 * v2;
    #pragma unroll
    for (int off = 1; off < 64; off <<= 1) {
        s  += __shfl_xor(s, off);
        ss += __shfl_xor(ss, off);
    }
    __shared__ float redS[4], redQ[4];
    const int wid = tid >> 6;
    if ((tid & 63) == 0) { redS[wid] = s; redQ[wid] = ss; }
    __syncthreads();
    s  = redS[0] + redS[1] + redS[2] + redS[3];
    ss = redQ[0] + redQ[1] + redQ[2] + redQ[3];
    const float mean = s * (1.0f / 768.0f);
    const float var  = ss * (1.0f / 768.0f) - mean * mean;
    const float rstd = rsqrtf(var + 1e-5f);
    int row_p = row;
    if (pad) {
        const unsigned bb = (unsigned)row / 577u;
        row_p = (int)(bb * 640u + ((unsigned)row - bb * 577u));
    }
    u16* ohr = oh + (size_t)row_p * 768;
    #pragma unroll
    for (int u = 0; u < 3; ++u) {
        const int c = tid + u * 256;
        const float vv = (u == 0) ? v0 : (u == 1) ? v1 : v2;
        ohr[c] = f2h((vv - mean) * rstd * g[c] + beta[c]);
    }
}

// ------------- fp16 MFMA GEMM: 256x256 tile, 8 waves, BK=32, ring-2 ---------
// Waves: wr = wid>>2 (2 M-halves of 128), wc = wid&3 (4 N-quarters of 64).
// Slot (32KB): A[256 rows][4 chunks x 8 fp16] | B same at +8192 u16. Ring-2.
// k-swizzle: phys chunk = kg ^ ((row>>1)&3); linear LDS dests (rule 21).
// LDS: OMODE2 = 69632B (scatter needs [64][68]/wave); else 65536B exactly
//      (2 blocks/CU). Epilogues in small per-wave passes, full-line stores.
// OMODE: 0 = fp32 out (+res), 1 = fp16 out, 2 = QKV scatter (batch-aligned).
// PADMAP (OMODE0): rows padded (b*640+n) -> orig b*577+n, skip pads.
template<int RELU6, int RES, int OMODE, int PADMAP>
__global__ __launch_bounds__(512, 2)
void mfma_gemm(const u16* __restrict__ Ah, const u16* __restrict__ Bh,
               const float* __restrict__ bias, const float* res,
               float* Cf, u16* __restrict__ Ch,
               u16* __restrict__ Qh_, u16* __restrict__ Kh_,
               u16* __restrict__ Vth_,
               int M, int N, int K)
{
    __shared__ u16 lds[(OMODE == 2) ? 34816 : 32768];

    const int tid  = threadIdx.x;
    const int wid  = tid >> 6;
    const int lane = tid & 63;
    const int wr = wid >> 2;                   // 0..1
    const int wc = wid & 3;                    // 0..3

    const int nwg = gridDim.x * gridDim.y;
    int lid = blockIdx.y * gridDim.x + blockIdx.x;
    lid = xcd_swz(lid, nwg);
    const int bm = (lid / gridDim.x) * 256;
    const int bn = (lid % gridDim.x) * 256;

    // staging: 2 A + 2 B loads per thread per phase; linear [row][chunk] dests
    const int trow = tid >> 2;                 // 0..127 (row within 128-row half)
    const int c    = tid & 3;                  // phys 16B chunk (4 per row)
    const u16* pA[2]; const u16* pB[2];
    char* dA[2]; char* dB[2];
    char* ldsb = (char*)lds;
    #pragma unroll
    for (int i = 0; i < 2; ++i) {
        const int r = i * 128 + trow;
        const int kg = c ^ ((r >> 1) & 3);
        pA[i] = Ah + (size_t)(bm + r) * K + kg * 8;
        pB[i] = Bh + (size_t)(bn + r) * K + kg * 8;
        dA[i] = ldsb +         i * 8192 + wid * 1024;
        dB[i] = ldsb + 16384 + i * 8192 + wid * 1024;
    }

    const int l15 = lane & 15;
    const int lg  = lane >> 4;

    f32x4 acc[8][4] = {};
    const int np = K >> 5;                     // phases (BK=32)

    // ---- prologue: stage phase 0 into slot 0 ----
    #pragma unroll
    for (int i = 0; i < 2; ++i) {
        load_lds16(pA[i], dA[i]); load_lds16(pB[i], dB[i]);
        pA[i] += 32; pB[i] += 32;
    }

    int cur = 0;
    for (int p = 0; p < np; ++p) {
        asm volatile("s_waitcnt vmcnt(0)" ::: "memory");
        __builtin_amdgcn_s_barrier();
        if (p + 1 < np) {                      // stage next phase -> other slot
            const int o = (cur ^ 1) * 32768;   // bytes
            #pragma unroll
            for (int i = 0; i < 2; ++i) {
                load_lds16(pA[i], dA[i] + o); load_lds16(pB[i], dB[i] + o);
                pA[i] += 32; pB[i] += 32;
            }
        }
        const u16* sA = lds + cur * 16384;     // u16 units
        const u16* sB = sA + 8192;

        f16x8 ah[8];
        #pragma unroll
        for (int fm = 0; fm < 8; ++fm) {
            const int ar = wr * 128 + fm * 16 + l15;
            const int pc = lg ^ ((ar >> 1) & 3);
            ah[fm] = *(const f16x8*)&sA[ar * 32 + pc * 8];
        }
        #pragma unroll
        for (int fn = 0; fn < 4; ++fn) {
            const int br = wc * 64 + fn * 16 + l15;
            const int pc = lg ^ ((br >> 1) & 3);
            const f16x8 bh = *(const f16x8*)&sB[br * 32 + pc * 8];
            #pragma unroll
            for (int fm = 0; fm < 8; ++fm)
                acc[fm][fn] = __builtin_amdgcn_mfma_f32_16x16x32_f16(
                    ah[fm], bh, acc[fm][fn], 0, 0, 0);
        }
        cur ^= 1;
    }

    __syncthreads();                           // retire all staging reads

    if (OMODE == 2) {
        // ---- batch-aligned QKV scatter, two 64-row passes per wave ----
        const int s  = bn / 768;               // 0=Q 1=K 2=V (uniform per block)
        const int hh = ((bn + wc * 64) - s * 768) >> 6;
        u16* eph = lds + wid * 4352;           // per-wave [64][68]
        #pragma unroll
        for (int h = 0; h < 2; ++h) {
            #pragma unroll
            for (int fn = 0; fn < 4; ++fn) {
                const float bv = bias[bn + wc * 64 + fn * 16 + l15];
                #pragma unroll
                for (int f2 = 0; f2 < 4; ++f2) {
                    const f32x4 v = acc[h * 4 + f2][fn];
                    #pragma unroll
                    for (int j = 0; j < 4; ++j) {
                        const float o = v[j] + bv;
                        const int idx = (s == 2)
                            ? (fn * 16 + l15) * 68 + f2 * 16 + lg * 4 + j
                            : (f2 * 16 + lg * 4 + j) * 68 + fn * 16 + l15;
                        eph[idx] = f2h(o);
                    }
                }
            }
            const int gr0 = bm + wr * 128 + h * 64;   // multiple of 64
            const int bb  = gr0 / 640;                // 64-row group: one batch
            const int n0  = gr0 - bb * 640;
            if (s == 2) {
                u16* dh = Vth_ + (size_t)(bb * 12 + hh) * 64 * 640 + n0 + lane;
                #pragma unroll 8
                for (int d = 0; d < 64; ++d)
                    dh[(size_t)d * 640] = eph[d * 68 + lane];
            } else {
                u16* base = ((s == 0) ? Qh_ : Kh_) +
                            ((size_t)(bb * 12 + hh) * 640 + n0) * 64 + lane;
                #pragma unroll 8
                for (int rr = 0; rr < 64; ++rr)
                    base[(size_t)rr * 64] = eph[rr * 68 + lane];
            }
        }
    } else if (OMODE == 1) {
        // ---- fp16 out: 4 passes x per-wave [32][68], 128B full-row stores ----
        u16* eph = lds + wid * 2176;           // per-wave [32][68] u16 (4352B)
        const int cc0 = bn + wc * 64;
        #pragma unroll
        for (int h = 0; h < 4; ++h) {
            #pragma unroll
            for (int fn = 0; fn < 4; ++fn) {
                const float bv = bias[cc0 + fn * 16 + l15];
                #pragma unroll
                for (int f2 = 0; f2 < 2; ++f2) {
                    const f32x4 v = acc[h * 2 + f2][fn];
                    #pragma unroll
                    for (int j = 0; j < 4; ++j) {
                        float o = v[j] + bv;
                        if (RELU6) o = fminf(fmaxf(o, 0.0f), 6.0f);
                        eph[(f2 * 16 + lg * 4 + j) * 68 + fn * 16 + l15] = f2h(o);
                    }
                }
            }
            #pragma unroll 8
            for (int rr = 0; rr < 32; ++rr) {
                const int r = bm + wr * 128 + h * 32 + rr;
                if (r < M)
                    Ch[(size_t)r * N + cc0 + lane] = eph[rr * 68 + lane];
            }
        }
    } else {
        // ---- fp32 out: 8 passes x per-wave [16][68] f32, 256B row stores ----
        float* epf = (float*)((char*)lds + wid * 4352);  // [16][68] f32
        const int cc0 = bn + wc * 64;
        #pragma unroll
        for (int h = 0; h < 8; ++h) {
            #pragma unroll
            for (int fn = 0; fn < 4; ++fn) {
                const float bv = bias[cc0 + fn * 16 + l15];
                const f32x4 v = acc[h][fn];
                #pragma unroll
                for (int j = 0; j < 4; ++j) {
                    float o = v[j] + bv;
                    if (RELU6) o = fminf(fmaxf(o, 0.0f), 6.0f);
                    epf[(lg * 4 + j) * 68 + fn * 16 + l15] = o;
                }
            }
            #pragma unroll 4
            for (int rr = 0; rr < 16; ++rr) {
                const int r = bm + wr * 128 + h * 16 + rr;
                float o = epf[rr * 68 + lane];
                if (PADMAP) {
                    const int bb2 = r / 640;
                    const int nn = r - bb2 * 640;
                    if (nn < 577) {
                        const size_t ro = (size_t)(bb2 * 577 + nn) * N + cc0 + lane;
                        if (RES) o += res[ro];
                        Cf[ro] = o;
                    }
                } else if (r < M) {
                    const size_t ro = (size_t)r * N + cc0 + lane;
                    if (RES) o += res[ro];
                    Cf[ro] = o;
                }
            }
        }
    }
}

// --------------------- MFMA flash attention (2-phase dbuf) ------------------
// Q/K: [bh][640][64] fp16 (batch-padded rows); Vt: [bh][64][640].
__global__ __launch_bounds__(256)
void attn_mfma(const u16* __restrict__ Qh, const u16* __restrict__ Kh,
               const u16* __restrict__ Vth, u16* __restrict__ Oh)
{
    constexpr int SEQ = 577, NP = 640;
    __shared__ u16 sK[2 * 4096], sV[2 * 4096];      // dbuf [row][64]
    __shared__ u16 sPh[4][16 * 72];                 // per-wave P / O-stage

    const int tid  = threadIdx.x;
    const int wave = tid >> 6;
    const int lane = tid & 63;
    const int l15 = lane & 15, lg = lane >> 4;

    const int nwg = gridDim.x * gridDim.y;
    int lid = blockIdx.y * gridDim.x + blockIdx.x;
    lid = xcd_swz(lid, nwg);
    const int q0 = (lid % gridDim.x) * 64;
    const int bh = lid / gridDim.x;

    const size_t qkBase = (size_t)bh * NP * 64;
    const size_t vBase  = (size_t)bh * 64 * NP;

    f16x8 qfh[2];
    {
        const size_t ro = qkBase + (size_t)(q0 + wave * 16 + l15) * 64;
        #pragma unroll
        for (int ks = 0; ks < 2; ++ks)
            qfh[ks] = *(const f16x8*)&Qh[ro + (ks * 4 + lg) * 8];
    }

    const int srow = lane >> 3;
    const int sc   = lane & 7;

    f32x4 oacc[4] = {};
    float mrun = -1e30f, lrun = 0.0f;
    constexpr int NT = 10;                          // ceil(577/64)

    // ---- prologue: stage kv tile 0 into buffer 0 ----
    #pragma unroll
    for (int t = 0; t < 2; ++t) {
        const int row = wave * 16 + t * 8 + srow;
        const int lc  = sc ^ (row & 7);
        load_lds16(Kh + qkBase + (size_t)row * 64 + lc * 8,
                   (char*)sK + wave * 2048 + t * 1024);
        load_lds16(Vth + vBase + (size_t)row * NP + lc * 8,
                   (char*)sV + wave * 2048 + t * 1024);
    }
    __syncthreads();

    int cur = 0;
    for (int it = 0; it < NT; ++it) {
        const int kv0 = it * 64;
        if (it + 1 < NT) {
            const int nkv = kv0 + 64;
            const int o = (cur ^ 1) * 8192;         // bytes
            #pragma unroll
            for (int t = 0; t < 2; ++t) {
                const int row = wave * 16 + t * 8 + srow;
                const int lc  = sc ^ (row & 7);
                load_lds16(Kh + qkBase + (size_t)(nkv + row) * 64 + lc * 8,
                           (char*)sK + o + wave * 2048 + t * 1024);
                load_lds16(Vth + vBase + (size_t)row * NP + nkv + lc * 8,
                           (char*)sV + o + wave * 2048 + t * 1024);
            }
        }
        const u16* sKc = sK + cur * 4096;
        const u16* sVc = sV + cur * 4096;

        // ---- S^T fragments: mfma(K, Q) ----
        f32x4 sacc[4] = {};
        __builtin_amdgcn_s_setprio(1);
        #pragma unroll
        for (int fkv = 0; fkv < 4; ++fkv) {
            const int row = fkv * 16 + l15;
            #pragma unroll
            for (int ks = 0; ks < 2; ++ks) {
                const int ph = ((ks * 4 + lg) ^ (row & 7)) * 8;
                const f16x8 kh = *(const f16x8*)&sKc[row * 64 + ph];
                sacc[fkv] = __builtin_amdgcn_mfma_f32_16x16x32_f16(
                    kh, qfh[ks], sacc[fkv], 0, 0, 0);
            }
        }
        __builtin_amdgcn_s_setprio(0);

        // ---- online softmax (lane holds 16 kv values of q=l15) ----
        float p[4][4];
        float mt = -1e30f;
        const bool tail = (kv0 + 64 > SEQ);
        #pragma unroll
        for (int fkv = 0; fkv < 4; ++fkv)
            #pragma unroll
            for (int j = 0; j < 4; ++j) {
                float sv = sacc[fkv][j] * 0.125f;
                if (tail && (kv0 + fkv * 16 + lg * 4 + j >= SEQ)) sv = -1e30f;
                p[fkv][j] = sv;
                mt = fmaxf(mt, sv);
            }
        mt = fmaxf(mt, __shfl_xor(mt, 16));
        mt = fmaxf(mt, __shfl_xor(mt, 32));
        const float mnew = fmaxf(mrun, mt);
        const float corr = __expf(mrun - mnew);
        float rs = 0.0f;
        #pragma unroll
        for (int fkv = 0; fkv < 4; ++fkv)
            #pragma unroll
            for (int j = 0; j < 4; ++j) {
                p[fkv][j] = __expf(p[fkv][j] - mnew);
                rs += p[fkv][j];
            }
        rs += __shfl_xor(rs, 16);
        rs += __shfl_xor(rs, 32);
        lrun = lrun * corr + rs;
        mrun = mnew;
        #pragma unroll
        for (int fd = 0; fd < 4; ++fd)
            #pragma unroll
            for (int j = 0; j < 4; ++j) oacc[fd][j] *= corr;

        // ---- P -> per-wave LDS (single fp16) ----
        u16* phr = &sPh[wave][l15 * 72];
        #pragma unroll
        for (int fkv = 0; fkv < 4; ++fkv) {
            ushort4 hv;
            hv.x = f2h(p[fkv][0]);
            hv.y = f2h(p[fkv][1]);
            hv.z = f2h(p[fkv][2]);
            hv.w = f2h(p[fkv][3]);
            *(ushort4*)&phr[fkv * 16 + lg * 4] = hv;
        }

        // ---- O^T += mfma(Vt, P) ----
        __builtin_amdgcn_s_setprio(1);
        #pragma unroll
        for (int ks = 0; ks < 2; ++ks) {
            const f16x8 pbh = *(const f16x8*)&sPh[wave][l15 * 72 + (ks * 4 + lg) * 8];
            #pragma unroll
            for (int fd = 0; fd < 4; ++fd) {
                const int row = fd * 16 + l15;
                const int ph = ((ks * 4 + lg) ^ (row & 7)) * 8;
                const f16x8 vh = *(const f16x8*)&sVc[row * 64 + ph];
                oacc[fd] = __builtin_amdgcn_mfma_f32_16x16x32_f16(
                    vh, pbh, oacc[fd], 0, 0, 0);
            }
        }
        __builtin_amdgcn_s_setprio(0);

        __syncthreads();
        cur ^= 1;
    }

    // ---- O store: stage per-wave LDS, then 128B full-row stores ----
    {
        const float inv = 1.0f / lrun;
        const int b = bh / 12, h = bh % 12;
        u16* ep = &sPh[wave][0];                // per-wave [16][68]
        #pragma unroll
        for (int fd = 0; fd < 4; ++fd) {
            ushort4 hv;
            hv.x = f2h(oacc[fd][0] * inv);
            hv.y = f2h(oacc[fd][1] * inv);
            hv.z = f2h(oacc[fd][2] * inv);
            hv.w = f2h(oacc[fd][3] * inv);
            *(ushort4*)&ep[l15 * 68 + fd * 16 + lg * 4] = hv;
        }
        #pragma unroll 4
        for (int rr = 0; rr < 16; ++rr) {
            const int q = q0 + wave * 16 + rr;
            if (q < SEQ)
                Oh[((size_t)(b * 640 + q)) * 768 + h * 64 + lane] =
                    ep[rr * 68 + lane];
        }
    }
}

// ------------------------------- launch ------------------------------------
extern "C" void kernel_launch(void* const* d_in, const int* in_sizes, int n_in,
                              void* d_out, int out_size, void* d_ws, size_t ws_size,
                              hipStream_t stream)
{
    const float* x      = (const float*)d_in[0];
    const float* ln1_g  = (const float*)d_in[1];
    const float* ln1_b  = (const float*)d_in[2];
    const float* ln2_g  = (const float*)d_in[3];
    const float* ln2_b  = (const float*)d_in[4];
    const float* w_qkv  = (const float*)d_in[5];
    const float* b_qkv  = (const float*)d_in[6];
    const float* w_proj = (const float*)d_in[7];
    const float* b_proj = (const float*)d_in[8];
    const float* w_fc1  = (const float*)d_in[9];
    const float* b_fc1  = (const float*)d_in[10];
    const float* w_fc2  = (const float*)d_in[11];
    const float* b_fc2  = (const float*)d_in[12];
    float* out = (float*)d_out;

    const int M  = 18464;       // real rows
    const int Mq = 20480;       // batch-padded rows (32 x 640 = 80 x 256)
    const int Mf = 18688;       // 73 x 256 (MLP tile space)

    // ---- workspace carve-up (~254.8 MB; 255.5 MB proven available) ----
    char* p = (char*)d_ws;
    u16* Wqkv  = (u16*)p;    p += (size_t)2304 * 768 * 2;
    u16* Wproj = (u16*)p;    p += (size_t)768 * 768 * 2;
    u16* Wfc1  = (u16*)p;    p += (size_t)3072 * 768 * 2;
    u16* Wfc2  = (u16*)p;    p += (size_t)768 * 3072 * 2;
    u16* A_h = (u16*)p;      p += (size_t)Mq * 768 * 2;      // padded act buf
    u16* Qh  = (u16*)p;      p += (size_t)384 * 640 * 64 * 2;
    u16* Kh  = (u16*)p;      p += (size_t)384 * 640 * 64 * 2;
    u16* Vth = (u16*)p;      p += (size_t)384 * 64 * 640 * 2;
    u16* fc1h = (u16*)p;     p += (size_t)Mf * 3072 * 2;     // full-M fc1 out

    // ---- weight prep ----
    wprep_kernel<<<dim3(72, 24),  256, 0, stream>>>(w_qkv,  Wqkv,  768, 2304);
    wprep_kernel<<<dim3(24, 24),  256, 0, stream>>>(w_proj, Wproj, 768, 768);
    wprep_kernel<<<dim3(96, 24),  256, 0, stream>>>(w_fc1,  Wfc1,  768, 3072);
    wprep_kernel<<<dim3(24, 96),  256, 0, stream>>>(w_fc2,  Wfc2,  3072, 768);

    // ---- ln1 -> A (padded rows) ----
    ln_kernel<<<M, 256, 0, stream>>>(x, ln1_g, ln1_b, A_h, 1);
    // ---- qkv projection over padded rows, aligned scatter into Q/K/Vt ----
    mfma_gemm<0, 0, 2, 0><<<dim3(9, 80), 512, 0, stream>>>(
        A_h, Wqkv, b_qkv, nullptr, nullptr, nullptr,
        Qh, Kh, Vth, Mq, 2304, 768);
    // ---- attention -> A (padded rows) ----
    attn_mfma<<<dim3(10, 384), 256, 0, stream>>>(Qh, Kh, Vth, A_h);
    // ---- x1 = attnO @ w_proj + b + x -> out (padded A rows -> orig C rows) ----
    mfma_gemm<0, 1, 0, 1><<<dim3(3, 80), 512, 0, stream>>>(
        A_h, Wproj, b_proj, x, out, nullptr,
        nullptr, nullptr, nullptr, Mq, 768, 768);
    // ---- ln2 -> A (unpadded rows) ----
    ln_kernel<<<M, 256, 0, stream>>>(out, ln2_g, ln2_b, A_h, 0);
    // ---- fc1 (73 m-tiles), relu6, fp16 out ----
    mfma_gemm<1, 0, 1, 0><<<dim3(12, 73), 512, 0, stream>>>(
        A_h, Wfc1, b_fc1, nullptr, nullptr, fc1h,
        nullptr, nullptr, nullptr, M, 3072, 768);
    // ---- fc2 (73 m-tiles) + residual -> out ----
    mfma_gemm<0, 1, 0, 0><<<dim3(3, 73), 512, 0, stream>>>(
        fc1h, Wfc2, b_fc2, out, out, nullptr,
        nullptr, nullptr, nullptr, M, 768, 3072);
}

// Round 21
// 566.376 us; speedup vs baseline: 1.0706x; 1.0706x over previous
//
#include <hip/hip_runtime.h>
#include <math.h>

// ---------------------------------------------------------------------------
// ViT encoder block. All-single-fp16 MFMA GEMMs + attention.
// B=32, N=577, D=768, H=12, Dh=64, hid=3072, M=18464, Mq=20480 (32x640).
// R21 = R18 (best measured: 571us) + T5 setprio around GEMM MFMA cluster.
//   GEMM: 256^2 tile, 8 waves, BK=64, ring-2 (128KB LDS), vmcnt(0)+barrier
//   per K-tile; LDS-staged full-line epilogues; batch-aligned QKV scatter.
//   BK=32 variants (R19/R20) measured worse; occupancy counter deemed
//   unreliable (gfx94x formula fallback) -- dur_us/FETCH/WRITE are the truth.
// ---------------------------------------------------------------------------

typedef unsigned short u16;
typedef _Float16 f16;
typedef __attribute__((ext_vector_type(8))) _Float16 f16x8;
typedef __attribute__((ext_vector_type(4))) float f32x4;

__device__ __forceinline__ u16 f2h(float x) {            // RNE f32 -> fp16 bits
    union { f16 h; u16 u; } cv;
    cv.h = (f16)x;
    return cv.u;
}
__device__ __forceinline__ float h2f(u16 b) {
    union { u16 u; f16 h; } cv;
    cv.u = b;
    return (float)cv.h;
}
__device__ __forceinline__ void load_lds16(const u16* g, void* l) {
    __builtin_amdgcn_global_load_lds(
        (const __attribute__((address_space(1))) void*)g,
        (__attribute__((address_space(3))) void*)l, 16, 0, 0);
}
// bijective XCD-chunk swizzle (m204)
__device__ __forceinline__ int xcd_swz(int lid, int nwg) {
    const int x = lid & 7, pos = lid >> 3;
    const int q = nwg >> 3, r = nwg & 7;
    return (x < r ? x * (q + 1) : r * (q + 1) + (x - r) * q) + pos;
}

// --------------------- weight transpose + fp16 (once) ----------------------
__global__ __launch_bounds__(256)
void wprep_kernel(const float* __restrict__ W, u16* __restrict__ Th,
                  int K, int N)
{
    __shared__ float t[32][33];
    const int n0 = blockIdx.x * 32, k0 = blockIdx.y * 32;
    const int tr = threadIdx.x >> 3, tc4 = (threadIdx.x & 7) * 4;
    const float4 v = *(const float4*)&W[(size_t)(k0 + tr) * N + n0 + tc4];
    t[tr][tc4 + 0] = v.x; t[tr][tc4 + 1] = v.y;
    t[tr][tc4 + 2] = v.z; t[tr][tc4 + 3] = v.w;
    __syncthreads();
    ushort4 h;
    h.x = f2h(t[tc4 + 0][tr]);
    h.y = f2h(t[tc4 + 1][tr]);
    h.z = f2h(t[tc4 + 2][tr]);
    h.w = f2h(t[tc4 + 3][tr]);
    *(ushort4*)&Th[(size_t)(n0 + tr) * K + k0 + tc4] = h;
}

// ------------------------- LayerNorm -> single fp16 -------------------------
// pad=1: write to batch-padded row (row/577)*640 + row%577; pad=0: direct.
__global__ __launch_bounds__(256)
void ln_kernel(const float* __restrict__ x, const float* __restrict__ g,
               const float* __restrict__ beta, u16* __restrict__ oh, int pad)
{
    const int row = blockIdx.x;
    const int tid = threadIdx.x;
    const float* xr = x + (size_t)row * 768;
    const float v0 = xr[tid], v1 = xr[tid + 256], v2 = xr[tid + 512];
    float s  = v0 + v1 + v2;
    float ss = v0 * v0 + v1 * v1 + v2 * v2;
    #pragma unroll
    for (int off = 1; off < 64; off <<= 1) {
        s  += __shfl_xor(s, off);
        ss += __shfl_xor(ss, off);
    }
    __shared__ float redS[4], redQ[4];
    const int wid = tid >> 6;
    if ((tid & 63) == 0) { redS[wid] = s; redQ[wid] = ss; }
    __syncthreads();
    s  = redS[0] + redS[1] + redS[2] + redS[3];
    ss = redQ[0] + redQ[1] + redQ[2] + redQ[3];
    const float mean = s * (1.0f / 768.0f);
    const float var  = ss * (1.0f / 768.0f) - mean * mean;
    const float rstd = rsqrtf(var + 1e-5f);
    int row_p = row;
    if (pad) {
        const unsigned bb = (unsigned)row / 577u;
        row_p = (int)(bb * 640u + ((unsigned)row - bb * 577u));
    }
    u16* ohr = oh + (size_t)row_p * 768;
    #pragma unroll
    for (int u = 0; u < 3; ++u) {
        const int c = tid + u * 256;
        const float vv = (u == 0) ? v0 : (u == 1) ? v1 : v2;
        ohr[c] = f2h((vv - mean) * rstd * g[c] + beta[c]);
    }
}

// --------------- fp16 MFMA GEMM: 256x256 tile, 8 waves, BK=64 ---------------
// Waves: wr = wid>>2 (2 M-halves of 128), wc = wid&3 (4 N-quarters of 64).
// Per wave: 8x4 frags of 16x16, 64 MFMA per K-tile. Ring-2 x 64KB slots.
// Epilogues: all LDS-staged per-wave, full-line global stores.
// OMODE: 0 = fp32 out (+res), 1 = fp16 out, 2 = QKV scatter (batch-aligned).
// PADMAP (OMODE0): rows padded (b*640+n) -> orig b*577+n, skip pads.
template<int RELU6, int RES, int OMODE, int PADMAP>
__global__ __launch_bounds__(512, 2)
void mfma_gemm(const u16* __restrict__ Ah, const u16* __restrict__ Bh,
               const float* __restrict__ bias, const float* res,
               float* Cf, u16* __restrict__ Ch,
               u16* __restrict__ Qh_, u16* __restrict__ Kh_,
               u16* __restrict__ Vth_,
               int M, int N, int K)
{
    __shared__ u16 lds[65536];                 // 2 slots x 64KB = 128KB

    const int tid  = threadIdx.x;
    const int wid  = tid >> 6;
    const int lane = tid & 63;
    const int wr = wid >> 2;                   // 0..1
    const int wc = wid & 3;                    // 0..3

    const int nwg = gridDim.x * gridDim.y;
    int lid = blockIdx.y * gridDim.x + blockIdx.x;
    lid = xcd_swz(lid, nwg);
    const int bm = (lid / gridDim.x) * 256;
    const int bn = (lid % gridDim.x) * 256;

    // staging: 4 A + 4 B loads per thread per K-tile; linear [row][chunk] dests
    const int trow = tid >> 3;                 // 0..63 (row within 64-row slice)
    const int c    = tid & 7;                  // phys 16B chunk
    const u16* pA[4]; const u16* pB[4];
    char* dA[4]; char* dB[4];
    char* ldsb = (char*)lds;
    #pragma unroll
    for (int i = 0; i < 4; ++i) {
        const int r = i * 64 + trow;
        const int kg = c ^ (r & 7);
        pA[i] = Ah + (size_t)(bm + r) * K + kg * 8;
        pB[i] = Bh + (size_t)(bn + r) * K + kg * 8;
        dA[i] = ldsb +         i * 8192 + wid * 1024;
        dB[i] = ldsb + 32768 + i * 8192 + wid * 1024;
    }

    const int l15 = lane & 15;
    const int lg  = lane >> 4;

    f32x4 acc[8][4] = {};
    const int np = K >> 6;                     // K-tiles (BK=64)

    // ---- prologue: stage K-tile 0 into slot 0 ----
    #pragma unroll
    for (int i = 0; i < 4; ++i) {
        load_lds16(pA[i], dA[i]); load_lds16(pB[i], dB[i]);
        pA[i] += 64; pB[i] += 64;
    }

    int cur = 0;
    for (int p = 0; p < np; ++p) {
        asm volatile("s_waitcnt vmcnt(0)" ::: "memory");
        __builtin_amdgcn_s_barrier();
        if (p + 1 < np) {                      // stage next K-tile -> other slot
            const int o = (cur ^ 1) * 65536;   // bytes
            #pragma unroll
            for (int i = 0; i < 4; ++i) {
                load_lds16(pA[i], dA[i] + o); load_lds16(pB[i], dB[i] + o);
                pA[i] += 64; pB[i] += 64;
            }
        }
        const u16* sA = lds + cur * 32768;     // u16 units
        const u16* sB = sA + 16384;

        __builtin_amdgcn_s_setprio(1);         // T5: favor MFMA-entering waves
        #pragma unroll
        for (int ss = 0; ss < 2; ++ss) {
            f16x8 ah[8];
            #pragma unroll
            for (int fm = 0; fm < 8; ++fm) {
                const int ar = wr * 128 + fm * 16 + l15;
                const int pc = (ss * 4 + lg) ^ (ar & 7);
                ah[fm] = *(const f16x8*)&sA[ar * 64 + pc * 8];
            }
            #pragma unroll
            for (int fn = 0; fn < 4; ++fn) {
                const int br = wc * 64 + fn * 16 + l15;
                const int pc = (ss * 4 + lg) ^ (br & 7);
                const f16x8 bh = *(const f16x8*)&sB[br * 64 + pc * 8];
                #pragma unroll
                for (int fm = 0; fm < 8; ++fm)
                    acc[fm][fn] = __builtin_amdgcn_mfma_f32_16x16x32_f16(
                        ah[fm], bh, acc[fm][fn], 0, 0, 0);
            }
        }
        __builtin_amdgcn_s_setprio(0);
        cur ^= 1;
    }

    __syncthreads();                           // retire all staging reads

    if (OMODE == 2) {
        // ---- batch-aligned QKV scatter, two 64-row passes per wave ----
        const int s  = bn / 768;               // 0=Q 1=K 2=V (uniform per block)
        const int hh = ((bn + wc * 64) - s * 768) >> 6;
        u16* eph = lds + wid * 4352;           // per-wave [64][68]
        #pragma unroll
        for (int h = 0; h < 2; ++h) {
            #pragma unroll
            for (int fn = 0; fn < 4; ++fn) {
                const float bv = bias[bn + wc * 64 + fn * 16 + l15];
                #pragma unroll
                for (int f2 = 0; f2 < 4; ++f2) {
                    const f32x4 v = acc[h * 4 + f2][fn];
                    #pragma unroll
                    for (int j = 0; j < 4; ++j) {
                        const float o = v[j] + bv;
                        const int idx = (s == 2)
                            ? (fn * 16 + l15) * 68 + f2 * 16 + lg * 4 + j
                            : (f2 * 16 + lg * 4 + j) * 68 + fn * 16 + l15;
                        eph[idx] = f2h(o);
                    }
                }
            }
            const int gr0 = bm + wr * 128 + h * 64;   // multiple of 64
            const int bb  = gr0 / 640;                // 64-row group: one batch
            const int n0  = gr0 - bb * 640;
            if (s == 2) {
                u16* dh = Vth_ + (size_t)(bb * 12 + hh) * 64 * 640 + n0 + lane;
                #pragma unroll 8
                for (int d = 0; d < 64; ++d)
                    dh[(size_t)d * 640] = eph[d * 68 + lane];
            } else {
                u16* base = ((s == 0) ? Qh_ : Kh_) +
                            ((size_t)(bb * 12 + hh) * 640 + n0) * 64 + lane;
                #pragma unroll 8
                for (int rr = 0; rr < 64; ++rr)
                    base[(size_t)rr * 64] = eph[rr * 68 + lane];
            }
        }
    } else if (OMODE == 1) {
        // ---- fp16 out: per-wave LDS stage, 128B full-row stores ----
        u16* eph = lds + wid * 4352;           // per-wave [64][68]
        const int cc0 = bn + wc * 64;
        #pragma unroll
        for (int h = 0; h < 2; ++h) {
            #pragma unroll
            for (int fn = 0; fn < 4; ++fn) {
                const float bv = bias[cc0 + fn * 16 + l15];
                #pragma unroll
                for (int f2 = 0; f2 < 4; ++f2) {
                    const f32x4 v = acc[h * 4 + f2][fn];
                    #pragma unroll
                    for (int j = 0; j < 4; ++j) {
                        float o = v[j] + bv;
                        if (RELU6) o = fminf(fmaxf(o, 0.0f), 6.0f);
                        eph[(f2 * 16 + lg * 4 + j) * 68 + fn * 16 + l15] = f2h(o);
                    }
                }
            }
            #pragma unroll 8
            for (int rr = 0; rr < 64; ++rr) {
                const int r = bm + wr * 128 + h * 64 + rr;
                if (r < M)
                    Ch[(size_t)r * N + cc0 + lane] = eph[rr * 68 + lane];
            }
        }
    } else {
        // ---- fp32 out: per-wave LDS stage, 256B full-row stores ----
        float* epf = (float*)lds + wid * (32 * 68);   // per-wave [32][68] f32
        const int cc0 = bn + wc * 64;
        #pragma unroll
        for (int h = 0; h < 4; ++h) {
            #pragma unroll
            for (int fn = 0; fn < 4; ++fn) {
                const float bv = bias[cc0 + fn * 16 + l15];
                #pragma unroll
                for (int f2 = 0; f2 < 2; ++f2) {
                    const f32x4 v = acc[h * 2 + f2][fn];
                    #pragma unroll
                    for (int j = 0; j < 4; ++j) {
                        float o = v[j] + bv;
                        if (RELU6) o = fminf(fmaxf(o, 0.0f), 6.0f);
                        epf[(f2 * 16 + lg * 4 + j) * 68 + fn * 16 + l15] = o;
                    }
                }
            }
            #pragma unroll 8
            for (int rr = 0; rr < 32; ++rr) {
                const int r = bm + wr * 128 + h * 32 + rr;
                float o = epf[rr * 68 + lane];
                if (PADMAP) {
                    const int bb2 = r / 640;
                    const int nn = r - bb2 * 640;
                    if (nn < 577) {
                        const size_t ro = (size_t)(bb2 * 577 + nn) * N + cc0 + lane;
                        if (RES) o += res[ro];
                        Cf[ro] = o;
                    }
                } else if (r < M) {
                    const size_t ro = (size_t)r * N + cc0 + lane;
                    if (RES) o += res[ro];
                    Cf[ro] = o;
                }
            }
        }
    }
}

// --------------------- MFMA flash attention (2-phase dbuf) ------------------
// Q/K: [bh][640][64] fp16 (batch-padded rows); Vt: [bh][64][640].
__global__ __launch_bounds__(256)
void attn_mfma(const u16* __restrict__ Qh, const u16* __restrict__ Kh,
               const u16* __restrict__ Vth, u16* __restrict__ Oh)
{
    constexpr int SEQ = 577, NP = 640;
    __shared__ u16 sK[2 * 4096], sV[2 * 4096];      // dbuf [row][64]
    __shared__ u16 sPh[4][16 * 72];                 // per-wave P / O-stage

    const int tid  = threadIdx.x;
    const int wave = tid >> 6;
    const int lane = tid & 63;
    const int l15 = lane & 15, lg = lane >> 4;

    const int nwg = gridDim.x * gridDim.y;
    int lid = blockIdx.y * gridDim.x + blockIdx.x;
    lid = xcd_swz(lid, nwg);
    const int q0 = (lid % gridDim.x) * 64;
    const int bh = lid / gridDim.x;

    const size_t qkBase = (size_t)bh * NP * 64;
    const size_t vBase  = (size_t)bh * 64 * NP;

    f16x8 qfh[2];
    {
        const size_t ro = qkBase + (size_t)(q0 + wave * 16 + l15) * 64;
        #pragma unroll
        for (int ks = 0; ks < 2; ++ks)
            qfh[ks] = *(const f16x8*)&Qh[ro + (ks * 4 + lg) * 8];
    }

    const int srow = lane >> 3;
    const int sc   = lane & 7;

    f32x4 oacc[4] = {};
    float mrun = -1e30f, lrun = 0.0f;
    constexpr int NT = 10;                          // ceil(577/64)

    // ---- prologue: stage kv tile 0 into buffer 0 ----
    #pragma unroll
    for (int t = 0; t < 2; ++t) {
        const int row = wave * 16 + t * 8 + srow;
        const int lc  = sc ^ (row & 7);
        load_lds16(Kh + qkBase + (size_t)row * 64 + lc * 8,
                   (char*)sK + wave * 2048 + t * 1024);
        load_lds16(Vth + vBase + (size_t)row * NP + lc * 8,
                   (char*)sV + wave * 2048 + t * 1024);
    }
    __syncthreads();

    int cur = 0;
    for (int it = 0; it < NT; ++it) {
        const int kv0 = it * 64;
        if (it + 1 < NT) {
            const int nkv = kv0 + 64;
            const int o = (cur ^ 1) * 8192;         // bytes
            #pragma unroll
            for (int t = 0; t < 2; ++t) {
                const int row = wave * 16 + t * 8 + srow;
                const int lc  = sc ^ (row & 7);
                load_lds16(Kh + qkBase + (size_t)(nkv + row) * 64 + lc * 8,
                           (char*)sK + o + wave * 2048 + t * 1024);
                load_lds16(Vth + vBase + (size_t)row * NP + nkv + lc * 8,
                           (char*)sV + o + wave * 2048 + t * 1024);
            }
        }
        const u16* sKc = sK + cur * 4096;
        const u16* sVc = sV + cur * 4096;

        // ---- S^T fragments: mfma(K, Q) ----
        f32x4 sacc[4] = {};
        __builtin_amdgcn_s_setprio(1);
        #pragma unroll
        for (int fkv = 0; fkv < 4; ++fkv) {
            const int row = fkv * 16 + l15;
            #pragma unroll
            for (int ks = 0; ks < 2; ++ks) {
                const int ph = ((ks * 4 + lg) ^ (row & 7)) * 8;
                const f16x8 kh = *(const f16x8*)&sKc[row * 64 + ph];
                sacc[fkv] = __builtin_amdgcn_mfma_f32_16x16x32_f16(
                    kh, qfh[ks], sacc[fkv], 0, 0, 0);
            }
        }
        __builtin_amdgcn_s_setprio(0);

        // ---- online softmax (lane holds 16 kv values of q=l15) ----
        float p[4][4];
        float mt = -1e30f;
        const bool tail = (kv0 + 64 > SEQ);
        #pragma unroll
        for (int fkv = 0; fkv < 4; ++fkv)
            #pragma unroll
            for (int j = 0; j < 4; ++j) {
                float sv = sacc[fkv][j] * 0.125f;
                if (tail && (kv0 + fkv * 16 + lg * 4 + j >= SEQ)) sv = -1e30f;
                p[fkv][j] = sv;
                mt = fmaxf(mt, sv);
            }
        mt = fmaxf(mt, __shfl_xor(mt, 16));
        mt = fmaxf(mt, __shfl_xor(mt, 32));
        const float mnew = fmaxf(mrun, mt);
        const float corr = __expf(mrun - mnew);
        float rs = 0.0f;
        #pragma unroll
        for (int fkv = 0; fkv < 4; ++fkv)
            #pragma unroll
            for (int j = 0; j < 4; ++j) {
                p[fkv][j] = __expf(p[fkv][j] - mnew);
                rs += p[fkv][j];
            }
        rs += __shfl_xor(rs, 16);
        rs += __shfl_xor(rs, 32);
        lrun = lrun * corr + rs;
        mrun = mnew;
        #pragma unroll
        for (int fd = 0; fd < 4; ++fd)
            #pragma unroll
            for (int j = 0; j < 4; ++j) oacc[fd][j] *= corr;

        // ---- P -> per-wave LDS (single fp16) ----
        u16* phr = &sPh[wave][l15 * 72];
        #pragma unroll
        for (int fkv = 0; fkv < 4; ++fkv) {
            ushort4 hv;
            hv.x = f2h(p[fkv][0]);
            hv.y = f2h(p[fkv][1]);
            hv.z = f2h(p[fkv][2]);
            hv.w = f2h(p[fkv][3]);
            *(ushort4*)&phr[fkv * 16 + lg * 4] = hv;
        }

        // ---- O^T += mfma(Vt, P) ----
        __builtin_amdgcn_s_setprio(1);
        #pragma unroll
        for (int ks = 0; ks < 2; ++ks) {
            const f16x8 pbh = *(const f16x8*)&sPh[wave][l15 * 72 + (ks * 4 + lg) * 8];
            #pragma unroll
            for (int fd = 0; fd < 4; ++fd) {
                const int row = fd * 16 + l15;
                const int ph = ((ks * 4 + lg) ^ (row & 7)) * 8;
                const f16x8 vh = *(const f16x8*)&sVc[row * 64 + ph];
                oacc[fd] = __builtin_amdgcn_mfma_f32_16x16x32_f16(
                    vh, pbh, oacc[fd], 0, 0, 0);
            }
        }
        __builtin_amdgcn_s_setprio(0);

        __syncthreads();
        cur ^= 1;
    }

    // ---- O store: stage per-wave LDS, then 128B full-row stores ----
    {
        const float inv = 1.0f / lrun;
        const int b = bh / 12, h = bh % 12;
        u16* ep = &sPh[wave][0];                // per-wave [16][68] (<=1152)
        #pragma unroll
        for (int fd = 0; fd < 4; ++fd) {
            ushort4 hv;
            hv.x = f2h(oacc[fd][0] * inv);
            hv.y = f2h(oacc[fd][1] * inv);
            hv.z = f2h(oacc[fd][2] * inv);
            hv.w = f2h(oacc[fd][3] * inv);
            *(ushort4*)&ep[l15 * 68 + fd * 16 + lg * 4] = hv;
        }
        #pragma unroll 4
        for (int rr = 0; rr < 16; ++rr) {
            const int q = q0 + wave * 16 + rr;
            if (q < SEQ)
                Oh[((size_t)(b * 640 + q)) * 768 + h * 64 + lane] =
                    ep[rr * 68 + lane];
        }
    }
}

// ------------------------------- launch ------------------------------------
extern "C" void kernel_launch(void* const* d_in, const int* in_sizes, int n_in,
                              void* d_out, int out_size, void* d_ws, size_t ws_size,
                              hipStream_t stream)
{
    const float* x      = (const float*)d_in[0];
    const float* ln1_g  = (const float*)d_in[1];
    const float* ln1_b  = (const float*)d_in[2];
    const float* ln2_g  = (const float*)d_in[3];
    const float* ln2_b  = (const float*)d_in[4];
    const float* w_qkv  = (const float*)d_in[5];
    const float* b_qkv  = (const float*)d_in[6];
    const float* w_proj = (const float*)d_in[7];
    const float* b_proj = (const float*)d_in[8];
    const float* w_fc1  = (const float*)d_in[9];
    const float* b_fc1  = (const float*)d_in[10];
    const float* w_fc2  = (const float*)d_in[11];
    const float* b_fc2  = (const float*)d_in[12];
    float* out = (float*)d_out;

    const int M  = 18464;       // real rows
    const int Mq = 20480;       // batch-padded rows (32 x 640 = 80 x 256)
    const int Mf = 18688;       // 73 x 256 (MLP tile space)

    // ---- workspace carve-up (~254.8 MB; 255.5 MB proven available) ----
    char* p = (char*)d_ws;
    u16* Wqkv  = (u16*)p;    p += (size_t)2304 * 768 * 2;
    u16* Wproj = (u16*)p;    p += (size_t)768 * 768 * 2;
    u16* Wfc1  = (u16*)p;    p += (size_t)3072 * 768 * 2;
    u16* Wfc2  = (u16*)p;    p += (size_t)768 * 3072 * 2;
    u16* A_h = (u16*)p;      p += (size_t)Mq * 768 * 2;      // padded act buf
    u16* Qh  = (u16*)p;      p += (size_t)384 * 640 * 64 * 2;
    u16* Kh  = (u16*)p;      p += (size_t)384 * 640 * 64 * 2;
    u16* Vth = (u16*)p;      p += (size_t)384 * 64 * 640 * 2;
    u16* fc1h = (u16*)p;     p += (size_t)Mf * 3072 * 2;     // full-M fc1 out

    // ---- weight prep ----
    wprep_kernel<<<dim3(72, 24),  256, 0, stream>>>(w_qkv,  Wqkv,  768, 2304);
    wprep_kernel<<<dim3(24, 24),  256, 0, stream>>>(w_proj, Wproj, 768, 768);
    wprep_kernel<<<dim3(96, 24),  256, 0, stream>>>(w_fc1,  Wfc1,  768, 3072);
    wprep_kernel<<<dim3(24, 96),  256, 0, stream>>>(w_fc2,  Wfc2,  3072, 768);

    // ---- ln1 -> A (padded rows) ----
    ln_kernel<<<M, 256, 0, stream>>>(x, ln1_g, ln1_b, A_h, 1);
    // ---- qkv projection over padded rows, aligned scatter into Q/K/Vt ----
    mfma_gemm<0, 0, 2, 0><<<dim3(9, 80), 512, 0, stream>>>(
        A_h, Wqkv, b_qkv, nullptr, nullptr, nullptr,
        Qh, Kh, Vth, Mq, 2304, 768);
    // ---- attention -> A (padded rows) ----
    attn_mfma<<<dim3(10, 384), 256, 0, stream>>>(Qh, Kh, Vth, A_h);
    // ---- x1 = attnO @ w_proj + b + x -> out (padded A rows -> orig C rows) ----
    mfma_gemm<0, 1, 0, 1><<<dim3(3, 80), 512, 0, stream>>>(
        A_h, Wproj, b_proj, x, out, nullptr,
        nullptr, nullptr, nullptr, Mq, 768, 768);
    // ---- ln2 -> A (unpadded rows) ----
    ln_kernel<<<M, 256, 0, stream>>>(out, ln2_g, ln2_b, A_h, 0);
    // ---- fc1 (73 m-tiles), relu6, fp16 out ----
    mfma_gemm<1, 0, 1, 0><<<dim3(12, 73), 512, 0, stream>>>(
        A_h, Wfc1, b_fc1, nullptr, nullptr, fc1h,
        nullptr, nullptr, nullptr, M, 3072, 768);
    // ---- fc2 (73 m-tiles) + residual -> out ----
    mfma_gemm<0, 1, 0, 0><<<dim3(3, 73), 512, 0, stream>>>(
        fc1h, Wfc2, b_fc2, out, out, nullptr,
        nullptr, nullptr, nullptr, M, 768, 3072);
}